// Round 6
// baseline (469.212 us; speedup 1.0000x reference)
//
#include <hip/hip_runtime.h>
#include <hip/hip_bf16.h>
#include <cstdint>
#include <cstddef>

#define N_TOK 8192
#define D_IN  1024
#define D_OUT 1024
#define N_EXP 8
#define KTOT  (N_EXP * D_IN)

#define BM    256
#define BN    128
#define BKH   32          // half-K step
#define NSTEP 256         // KTOT / BKH

typedef __attribute__((ext_vector_type(8))) short short8;
typedef __attribute__((ext_vector_type(8))) unsigned short ushort8;
typedef __attribute__((ext_vector_type(4))) float f32x4;

__device__ __forceinline__ unsigned short f2bf(float f) {
    union { float f; unsigned int u; } v; v.f = f;
    return (unsigned short)((v.u + 0x7FFFu + ((v.u >> 16) & 1u)) >> 16);
}

__device__ __forceinline__ void load_lds16(const void* g, void* l) {
    __builtin_amdgcn_global_load_lds(
        (const __attribute__((address_space(1))) void*)g,
        (__attribute__((address_space(3))) void*)l,
        16, 0, 0);
}

// ---------------------------------------------------------------------------
// Fused prep, 4096 blocks (UNCHANGED):
//   [0,2048)    : W[e][i][o] fp32 -> Wt[o][e*1024+i] bf16 (64x64 transpose)
//   [2048,4096) : gate softmax + x->bf16, one wave per token (4 tok/block)
// ---------------------------------------------------------------------------
__global__ __launch_bounds__(256) void prep_kernel(
    const float* __restrict__ x, const float* __restrict__ gW,
    const float* __restrict__ gbias, const float* __restrict__ W,
    unsigned short* __restrict__ xb, unsigned short* __restrict__ Wt,
    float* __restrict__ g_t) {
    const int b = blockIdx.x;
    const int t = threadIdx.x;

    if (b < 2048) {
        __shared__ float tile[64][65];
        const int e  = b >> 8;
        const int i0 = ((b >> 4) & 15) * 64;
        const int o0 = (b & 15) * 64;

        const int rr = t >> 4;
        const int rc = (t & 15) * 4;
#pragma unroll
        for (int j = 0; j < 4; ++j) {
            const float4 v = *(const float4*)(
                W + ((size_t)e * D_IN + (i0 + rr + 16 * j)) * D_OUT + o0 + rc);
            tile[rr + 16 * j][rc + 0] = v.x;
            tile[rr + 16 * j][rc + 1] = v.y;
            tile[rr + 16 * j][rc + 2] = v.z;
            tile[rr + 16 * j][rc + 3] = v.w;
        }
        __syncthreads();
        const int ow = t >> 2;
        const int c  = (t & 3) * 16;
        ushort8 v0, v1;
#pragma unroll
        for (int j = 0; j < 8; ++j) v0[j] = f2bf(tile[c + j][ow]);
#pragma unroll
        for (int j = 0; j < 8; ++j) v1[j] = f2bf(tile[c + 8 + j][ow]);
        unsigned short* dst = Wt + (size_t)(o0 + ow) * KTOT + e * D_IN + i0 + c;
        *(ushort8*)dst = v0;
        *(ushort8*)(dst + 8) = v1;
    } else {
        const int lane = t & 63;
        const int n    = (b - 2048) * 4 + (t >> 6);

        float acc[8];
#pragma unroll
        for (int e = 0; e < 8; ++e) acc[e] = 0.f;
#pragma unroll
        for (int jj = 0; jj < 4; ++jj) {
            const int i = 256 * jj + 4 * lane;
            const float4 xv = *(const float4*)(x + (size_t)n * D_IN + i);
            ushort4 u;
            u.x = f2bf(xv.x); u.y = f2bf(xv.y);
            u.z = f2bf(xv.z); u.w = f2bf(xv.w);
            *(ushort4*)(xb + (size_t)n * D_IN + i) = u;
            const float xs[4] = {xv.x, xv.y, xv.z, xv.w};
#pragma unroll
            for (int j = 0; j < 4; ++j) {
                const float* wr = gW + (size_t)(i + j) * N_EXP;
                const float4 w0 = *(const float4*)wr;
                const float4 w1 = *(const float4*)(wr + 4);
                acc[0] += xs[j] * w0.x; acc[1] += xs[j] * w0.y;
                acc[2] += xs[j] * w0.z; acc[3] += xs[j] * w0.w;
                acc[4] += xs[j] * w1.x; acc[5] += xs[j] * w1.y;
                acc[6] += xs[j] * w1.z; acc[7] += xs[j] * w1.w;
            }
        }
#pragma unroll
        for (int off = 32; off > 0; off >>= 1) {
#pragma unroll
            for (int e = 0; e < 8; ++e) acc[e] += __shfl_down(acc[e], off);
        }
        if (lane == 0) {
            float lg[8], mx = -1e30f;
#pragma unroll
            for (int e = 0; e < 8; ++e) {
                lg[e] = acc[e] + gbias[e];
                mx = fmaxf(mx, lg[e]);
            }
            float s = 0.f;
#pragma unroll
            for (int e = 0; e < 8; ++e) { lg[e] = expf(lg[e] - mx); s += lg[e]; }
            const float inv = 1.f / s;
#pragma unroll
            for (int e = 0; e < 8; ++e)
                g_t[(size_t)e * N_TOK + n] = lg[e] * inv;
        }
    }
}

// ---------------------------------------------------------------------------
// GEMM v14 = v13 (BM256xBN128, 8 waves, XCD 4Mx8N super-tile, A XOR swizzle,
// interleaved MFMA/ds_read, telescoping rescale) with B FRAGMENTS LOADED
// DIRECT FROM L2 (register double-buffer), bypassing LDS:
//   - LDS port demand/step: 88 KB (1035 cyc) -> 48 KB (565 cyc) < MFMA 621.
//   - B panel is 2 MB/XCD, L2-resident (R2). Quad lanes read consecutive
//     16B of one 64B line; 4 M-waves read identical lines per step -> L1
//     filters 3/4. B(h+1) issued at top of step h (~600 cyc > L2 latency).
//   - vmcnt FIFO per step: issue [B(h+1)x4, Astage(h+3)x2]; ENDW vmcnt(2)
//     drains A(h+2) (cluster(h+1) ds_reads) + B(h+1) (MFMA h+1), leaves
//     A(h+3) in flight across the barrier. Never drains to 0 mid-loop.
// ---------------------------------------------------------------------------
__global__ __launch_bounds__(512, 1) void moe_gemm14_kernel(
    const unsigned short* __restrict__ xb,   // [N_TOK][D_IN] bf16
    const unsigned short* __restrict__ Wt,   // [D_OUT][KTOT] bf16
    const float* __restrict__ bias,          // [N_EXP][D_OUT]
    const float* __restrict__ g_t,           // [N_EXP][N_TOK]
    float* __restrict__ out) {               // [N_TOK][D_OUT]
    __shared__ __align__(16) unsigned short A4[4][BM * BKH];  // 64 KB
    __shared__ __align__(16) float g_s[N_EXP][BM];            // 8 KB
    __shared__ __align__(16) float r_s[N_EXP][BM];            // 8 KB
    __shared__ __align__(16) float b_s[N_EXP][BN];            // 4 KB

    const int t    = threadIdx.x;
    const int lane = t & 63;
    const int ln15 = lane & 15;
    const int quad = lane >> 4;
    const int wave = t >> 6;             // 0..7
    const int wm0  = (wave >> 1) * 64;   // 0,64,128,192
    const int wn0  = (wave & 1) * 64;    // 0,64

    // XCD super-tile: flat%8 = XCD; XCD owns M-rows [4*xcd,4*xcd+4) x 8 N-cols
    // -> per-XCD per-expert working set 4MB = L2 (R2: FETCH 533->79MB).
    const int flat = blockIdx.x + 8 * blockIdx.y;   // grid (8, 32)
    const int bn0  = ((flat >> 3) & 7) * BN;
    const int bm0  = ((flat & 7) * 4 + (flat >> 6)) * BM;

    for (int j = t; j < N_EXP * BM; j += 512)
        g_s[j >> 8][j & 255] = g_t[(size_t)(j >> 8) * N_TOK + bm0 + (j & 255)];
    for (int j = t; j < N_EXP * BN; j += 512)
        b_s[j >> 7][j & 127] = bias[(size_t)(j >> 7) * D_OUT + bn0 + (j & 127)];
    __syncthreads();
    if (t < BM) {
        float d[N_EXP];
#pragma unroll
        for (int e = 0; e < N_EXP; ++e) d[e] = fmaxf(g_s[e][t], 1e-30f);
#pragma unroll
        for (int e = 1; e < N_EXP; ++e) r_s[e][t] = d[e - 1] / d[e];
        r_s[0][t] = d[N_EXP - 1];
    }
    __syncthreads();   // r_s ready

    f32x4 acc[4][4];
#pragma unroll
    for (int mi = 0; mi < 4; ++mi)
#pragma unroll
        for (int ni = 0; ni < 4; ++ni)
            acc[mi][ni] = (f32x4){0.f, 0.f, 0.f, 0.f};

    // A staging: thread t fills slot (row t>>2 [+128], chunk t&3); swizzled
    // global source so slot chunk c' holds global chunk c'^((row>>1)&3).
    const int csw  = ((t & 3) ^ ((t >> 3) & 3)) * 8;
    const unsigned short* gA = xb + (size_t)(bm0 + (t >> 2)) * D_IN + csw;
    const int wrow = wave * 16 * BKH;   // wave-uniform LDS base

    // A fragment reads: chunk slot = quad ^ ((ln15>>1)&3)  (0-conflict)
    const int ksw  = (quad ^ ((ln15 >> 1) & 3)) * 8;
    const int aoff = (wm0 + ln15) * BKH + ksw;

    // B fragments direct from global: lane reads 16B at row bn0+wn0+ni*16+
    // ln15, k-offset h*32 + quad*8. Quads cover one 64B line per row.
    const unsigned short* gBf =
        Wt + (size_t)(bn0 + wn0 + ln15) * KTOT + quad * 8;

    // Named register buffers (static indexing — rule #20).
    short8 afA[4], afB[4], bvA[4], bvB[4];

    // prologue: B(0)->bvA, stage A slots 0,1,2. Queue [B0x4,A0x2,A1x2,A2x2];
    // vmcnt(2) drains B0,A0,A1 (A1 needed by cluster(0) ds_reads), leaves A2
    // -> exactly the steady state entering step 0.
#pragma unroll
    for (int ni = 0; ni < 4; ++ni)
        bvA[ni] = *(const short8*)(gBf + (size_t)ni * 16 * KTOT);
#pragma unroll
    for (int s = 0; s < 3; ++s) {
        load_lds16(gA + s * BKH,              &A4[s][wrow]);
        load_lds16(gA + 128 * D_IN + s * BKH, &A4[s][128 * BKH + wrow]);
    }
    asm volatile("s_waitcnt vmcnt(2)" ::: "memory");
    __builtin_amdgcn_s_barrier();
    __builtin_amdgcn_sched_barrier(0);
#pragma unroll
    for (int mi = 0; mi < 4; ++mi)
        afA[mi] = *(const short8*)(&A4[0][0] + aoff + mi * 16 * BKH);

#define MFMA4(CUR, mi_)                                                       \
    _Pragma("unroll") for (int ni = 0; ni < 4; ++ni)                          \
        acc[mi_][ni] = __builtin_amdgcn_mfma_f32_16x16x32_bf16(               \
            af##CUR[mi_], bv##CUR[ni], acc[mi_][ni], 0, 0, 0);

// Step h: [B(h+1)->bvNXT] [stage A(h+3)] lgkm0 [rescale?]
//         {MFMA quartet ; ds_read A-frag(h+1)->afNXT} x4
// Safety (1 barrier/step): wave's slot-h ds_reads done before its lgkm0(h)
// < barrier ENDW(h) < stage into that slot at h+2 (two barriers later).
#define STEP(h_, CUR, NXT, DO_STAGE, DO_BLOAD, DO_READ)                       \
  {                                                                           \
    const int hs_ = (h_) + 3;                                                 \
    const unsigned short* An_ = &A4[((h_) + 1) & 3][0];                       \
    if (DO_BLOAD) {                                                           \
      _Pragma("unroll") for (int ni = 0; ni < 4; ++ni)                        \
        bv##NXT[ni] = *(const short8*)(                                       \
            gBf + (size_t)ni * 16 * KTOT + ((h_) + 1) * 32);                  \
    }                                                                         \
    if (DO_STAGE) {                                                           \
      load_lds16(gA + ((hs_) & 31) * BKH,              &A4[(hs_) & 3][wrow]); \
      load_lds16(gA + 128 * D_IN + ((hs_) & 31) * BKH,                        \
                 &A4[(hs_) & 3][128 * BKH + wrow]);                           \
    }                                                                         \
    asm volatile("s_waitcnt lgkmcnt(0)" ::: "memory");                        \
    __builtin_amdgcn_sched_barrier(0);                                        \
    if ((h_) && !((h_) & 31)) {  /* telescoping rescale at expert entry */    \
      const int e_ = (h_) >> 5;                                               \
      _Pragma("unroll") for (int mi = 0; mi < 4; ++mi) {                      \
        const f32x4 rv = *(const f32x4*)&r_s[e_][wm0 + mi * 16 + quad * 4];   \
        _Pragma("unroll") for (int ni = 0; ni < 4; ++ni)                      \
          _Pragma("unroll") for (int r = 0; r < 4; ++r)                       \
            acc[mi][ni][r] *= rv[r];                                          \
      }                                                                       \
    }                                                                         \
    __builtin_amdgcn_s_setprio(1);                                            \
    MFMA4(CUR, 0)                                                             \
    __builtin_amdgcn_sched_barrier(0);                                        \
    if (DO_READ)                                                              \
      af##NXT[0] = *(const short8*)(An_ + aoff + 0 * 16 * BKH);               \
    __builtin_amdgcn_sched_barrier(0);                                        \
    MFMA4(CUR, 1)                                                             \
    __builtin_amdgcn_sched_barrier(0);                                        \
    if (DO_READ)                                                              \
      af##NXT[1] = *(const short8*)(An_ + aoff + 1 * 16 * BKH);               \
    __builtin_amdgcn_sched_barrier(0);                                        \
    MFMA4(CUR, 2)                                                             \
    __builtin_amdgcn_sched_barrier(0);                                        \
    if (DO_READ) {                                                            \
      af##NXT[2] = *(const short8*)(An_ + aoff + 2 * 16 * BKH);               \
      af##NXT[3] = *(const short8*)(An_ + aoff + 3 * 16 * BKH);               \
    }                                                                         \
    __builtin_amdgcn_sched_barrier(0);                                        \
    MFMA4(CUR, 3)                                                             \
    __builtin_amdgcn_s_setprio(0);                                            \
    __builtin_amdgcn_sched_barrier(0);                                        \
  }

#define ENDW(N_)                                                              \
  asm volatile("s_waitcnt vmcnt(" #N_ ")" ::: "memory");                      \
  __builtin_amdgcn_s_barrier();                                               \
  __builtin_amdgcn_sched_barrier(0);

    for (int h = 0; h < NSTEP - 4; h += 2) {   // pairs (0,1)..(250,251)
        STEP(h, A, B, 1, 1, 1);
        ENDW(2);
        STEP(h + 1, B, A, 1, 1, 1);
        ENDW(2);
    }
    STEP(252, A, B, 1, 1, 1);   // stages A255 (last), loads B253
    ENDW(2);
    STEP(253, B, A, 0, 1, 1);   // loads B254, reads af254
    ENDW(0);                    // drain A255 (cluster 254 reads it) + B254
    STEP(254, A, B, 0, 1, 1);   // loads B255, reads af255
    ENDW(0);                    // drain B255
    STEP(255, B, A, 0, 0, 0);

#undef STEP
#undef MFMA4
#undef ENDW

    // final telescope scale by d[7], then add sum_e g_e * b[e][col]
#pragma unroll
    for (int mi = 0; mi < 4; ++mi) {
        const f32x4 fin = *(const f32x4*)&r_s[0][wm0 + mi * 16 + quad * 4];
#pragma unroll
        for (int ni = 0; ni < 4; ++ni)
#pragma unroll
            for (int r = 0; r < 4; ++r) acc[mi][ni][r] *= fin[r];
    }
#pragma unroll
    for (int e = 0; e < N_EXP; ++e) {
        f32x4 gv[4];
        float bb[4];
#pragma unroll
        for (int mi = 0; mi < 4; ++mi)
            gv[mi] = *(const f32x4*)&g_s[e][wm0 + mi * 16 + quad * 4];
#pragma unroll
        for (int ni = 0; ni < 4; ++ni) bb[ni] = b_s[e][wn0 + ni * 16 + ln15];
#pragma unroll
        for (int mi = 0; mi < 4; ++mi)
#pragma unroll
            for (int ni = 0; ni < 4; ++ni)
#pragma unroll
                for (int r = 0; r < 4; ++r)
                    acc[mi][ni][r] += gv[mi][r] * bb[ni];
    }

#pragma unroll
    for (int mi = 0; mi < 4; ++mi) {
#pragma unroll
        for (int ni = 0; ni < 4; ++ni) {
            const int col  = bn0 + wn0 + ni * 16 + ln15;
            const int row0 = bm0 + wm0 + mi * 16 + quad * 4;
#pragma unroll
            for (int r = 0; r < 4; ++r)
                out[(size_t)(row0 + r) * D_OUT + col] = acc[mi][ni][r];
        }
    }
}

// ---------------------------------------------------------------------------
extern "C" void kernel_launch(void* const* d_in, const int* in_sizes, int n_in,
                              void* d_out, int out_size, void* d_ws, size_t ws_size,
                              hipStream_t stream) {
    const float* x  = (const float*)d_in[0];
    const float* W  = (const float*)d_in[1];
    const float* b  = (const float*)d_in[2];
    const float* gW = (const float*)d_in[3];
    const float* gb = (const float*)d_in[4];
    float* out = (float*)d_out;

    unsigned short* xb  = (unsigned short*)d_ws;                 // 16 MB
    unsigned short* Wt  = xb + (size_t)N_TOK * D_IN;             // 16 MB
    float*          g_t = (float*)(Wt + (size_t)D_OUT * KTOT);   // 256 KB

    prep_kernel<<<4096, 256, 0, stream>>>(x, gW, gb, W, xb, Wt, g_t);
    moe_gemm14_kernel<<<dim3(D_OUT / BN, N_TOK / BM), 512, 0, stream>>>(
        xb, Wt, b, g_t, out);
}

// Round 7
// 381.964 us; speedup vs baseline: 1.2284x; 1.2284x over previous
//
#include <hip/hip_runtime.h>
#include <hip/hip_bf16.h>
#include <cstdint>
#include <cstddef>

#define N_TOK 8192
#define D_IN  1024
#define D_OUT 1024
#define N_EXP 8
#define KTOT  (N_EXP * D_IN)

#define BM    256
#define BN    128
#define BKH   32          // half-K step
#define NSTEP 256         // KTOT / BKH

typedef __attribute__((ext_vector_type(8))) short short8;
typedef __attribute__((ext_vector_type(8))) unsigned short ushort8;
typedef __attribute__((ext_vector_type(4))) float f32x4;

__device__ __forceinline__ unsigned short f2bf(float f) {
    union { float f; unsigned int u; } v; v.f = f;
    return (unsigned short)((v.u + 0x7FFFu + ((v.u >> 16) & 1u)) >> 16);
}

__device__ __forceinline__ void load_lds16(const void* g, void* l) {
    __builtin_amdgcn_global_load_lds(
        (const __attribute__((address_space(1))) void*)g,
        (__attribute__((address_space(3))) void*)l,
        16, 0, 0);
}

// ---------------------------------------------------------------------------
// Fused prep, 4096 blocks:
//   [0,2048)    : W[e][i][o] fp32 -> Wt FRAGMENT-MAJOR bf16:
//                 tile (o/16, k/32) is a contiguous 1KB block laid out as
//                 [o&15][quad=(k>>3)&3][k&7] — exactly the per-lane MFMA
//                 B-fragment order (lane(quad,ln15) reads ln15*64+quad*16 B).
//   [2048,4096) : gate softmax + x->bf16, one wave per token (unchanged)
// ---------------------------------------------------------------------------
__global__ __launch_bounds__(256) void prep_kernel(
    const float* __restrict__ x, const float* __restrict__ gW,
    const float* __restrict__ gbias, const float* __restrict__ W,
    unsigned short* __restrict__ xb, unsigned short* __restrict__ Wt,
    float* __restrict__ g_t) {
    const int b = blockIdx.x;
    const int t = threadIdx.x;

    if (b < 2048) {
        __shared__ float tile[64][65];
        const int e  = b >> 8;
        const int i0 = ((b >> 4) & 15) * 64;
        const int o0 = (b & 15) * 64;

        const int rr = t >> 4;
        const int rc = (t & 15) * 4;
#pragma unroll
        for (int j = 0; j < 4; ++j) {
            const float4 v = *(const float4*)(
                W + ((size_t)e * D_IN + (i0 + rr + 16 * j)) * D_OUT + o0 + rc);
            tile[rr + 16 * j][rc + 0] = v.x;
            tile[rr + 16 * j][rc + 1] = v.y;
            tile[rr + 16 * j][rc + 2] = v.z;
            tile[rr + 16 * j][rc + 3] = v.w;
        }
        __syncthreads();
        const int ow = t >> 2;
        const int c  = (t & 3) * 16;
        ushort8 v0, v1;
#pragma unroll
        for (int j = 0; j < 8; ++j) v0[j] = f2bf(tile[c + j][ow]);
#pragma unroll
        for (int j = 0; j < 8; ++j) v1[j] = f2bf(tile[c + 8 + j][ow]);
        // fragment-major dst: o = o0+ow, k0 = e*1024+i0+c (mult of 16)
        const int o  = o0 + ow;
        const int k0 = e * D_IN + i0 + c;
        unsigned short* dst =
            Wt + ((size_t)(o >> 4) * (KTOT >> 5) + (k0 >> 5)) * 512
               + (o & 15) * 32 + ((k0 >> 3) & 3) * 8;
        *(ushort8*)dst = v0;          // k0..k0+7   (quad q)
        *(ushort8*)(dst + 8) = v1;    // k0+8..+15  (quad q+1) — contiguous
    } else {
        const int lane = t & 63;
        const int n    = (b - 2048) * 4 + (t >> 6);

        float acc[8];
#pragma unroll
        for (int e = 0; e < 8; ++e) acc[e] = 0.f;
#pragma unroll
        for (int jj = 0; jj < 4; ++jj) {
            const int i = 256 * jj + 4 * lane;
            const float4 xv = *(const float4*)(x + (size_t)n * D_IN + i);
            ushort4 u;
            u.x = f2bf(xv.x); u.y = f2bf(xv.y);
            u.z = f2bf(xv.z); u.w = f2bf(xv.w);
            *(ushort4*)(xb + (size_t)n * D_IN + i) = u;
            const float xs[4] = {xv.x, xv.y, xv.z, xv.w};
#pragma unroll
            for (int j = 0; j < 4; ++j) {
                const float* wr = gW + (size_t)(i + j) * N_EXP;
                const float4 w0 = *(const float4*)wr;
                const float4 w1 = *(const float4*)(wr + 4);
                acc[0] += xs[j] * w0.x; acc[1] += xs[j] * w0.y;
                acc[2] += xs[j] * w0.z; acc[3] += xs[j] * w0.w;
                acc[4] += xs[j] * w1.x; acc[5] += xs[j] * w1.y;
                acc[6] += xs[j] * w1.z; acc[7] += xs[j] * w1.w;
            }
        }
#pragma unroll
        for (int off = 32; off > 0; off >>= 1) {
#pragma unroll
            for (int e = 0; e < 8; ++e) acc[e] += __shfl_down(acc[e], off);
        }
        if (lane == 0) {
            float lg[8], mx = -1e30f;
#pragma unroll
            for (int e = 0; e < 8; ++e) {
                lg[e] = acc[e] + gbias[e];
                mx = fmaxf(mx, lg[e]);
            }
            float s = 0.f;
#pragma unroll
            for (int e = 0; e < 8; ++e) { lg[e] = expf(lg[e] - mx); s += lg[e]; }
            const float inv = 1.f / s;
#pragma unroll
            for (int e = 0; e < 8; ++e)
                g_t[(size_t)e * N_TOK + n] = lg[e] * inv;
        }
    }
}

// ---------------------------------------------------------------------------
// GEMM v16 = v13 skeleton (BM256xBN128, 8 waves, XCD 4Mx8N super-tile, A in
// LDS with XOR swizzle, interleaved MFMA/ds_read, telescoping rescale) + B
// FRAGMENTS DIRECT FROM L2 in FRAGMENT-MAJOR layout:
//   - each per-step B fragment load = ONE contiguous 1KB block per wave
//     (sequential 64B lines; no L1 set aliasing — v14's 16KB-strided rows
//     aliased L1 dead and serialized L2 latency, 357us).
//   - waves sharing wn0 hit L1 (3/4 filtered); L2 sees ~8KB/step/CU stream.
//   - LDS port demand/step: 88KB (1035 cyc, R5-binding) -> 48KB (565 cyc)
//     < MFMA pipe 621 cyc.
//   - vmcnt FIFO/step: issue [B(h+1)x4, Astage(h+3)x2]; ENDW vmcnt(2)
//     drains B(h+1)+A(h+2), leaves A(h+3) in flight. Never 0 mid-loop.
// ---------------------------------------------------------------------------
__global__ __launch_bounds__(512, 1) void moe_gemm16_kernel(
    const unsigned short* __restrict__ xb,   // [N_TOK][D_IN] bf16
    const unsigned short* __restrict__ Wt,   // fragment-major (see prep)
    const float* __restrict__ bias,          // [N_EXP][D_OUT]
    const float* __restrict__ g_t,           // [N_EXP][N_TOK]
    float* __restrict__ out) {               // [N_TOK][D_OUT]
    __shared__ __align__(16) unsigned short A4[4][BM * BKH];  // 64 KB
    __shared__ __align__(16) float g_s[N_EXP][BM];            // 8 KB
    __shared__ __align__(16) float r_s[N_EXP][BM];            // 8 KB
    __shared__ __align__(16) float b_s[N_EXP][BN];            // 4 KB

    const int t    = threadIdx.x;
    const int lane = t & 63;
    const int ln15 = lane & 15;
    const int quad = lane >> 4;
    const int wave = t >> 6;             // 0..7
    const int wm0  = (wave >> 1) * 64;   // 0,64,128,192
    const int wn0  = (wave & 1) * 64;    // 0,64

    // XCD super-tile: flat%8 = XCD; XCD owns M-rows [4*xcd,4*xcd+4) x 8 N-cols
    // -> per-XCD per-expert working set 4MB = L2 (R2: FETCH 533->79MB).
    const int flat = blockIdx.x + 8 * blockIdx.y;   // grid (8, 32)
    const int bn0  = ((flat >> 3) & 7) * BN;
    const int bm0  = ((flat & 7) * 4 + (flat >> 6)) * BM;

    for (int j = t; j < N_EXP * BM; j += 512)
        g_s[j >> 8][j & 255] = g_t[(size_t)(j >> 8) * N_TOK + bm0 + (j & 255)];
    for (int j = t; j < N_EXP * BN; j += 512)
        b_s[j >> 7][j & 127] = bias[(size_t)(j >> 7) * D_OUT + bn0 + (j & 127)];
    __syncthreads();
    if (t < BM) {
        float d[N_EXP];
#pragma unroll
        for (int e = 0; e < N_EXP; ++e) d[e] = fmaxf(g_s[e][t], 1e-30f);
#pragma unroll
        for (int e = 1; e < N_EXP; ++e) r_s[e][t] = d[e - 1] / d[e];
        r_s[0][t] = d[N_EXP - 1];
    }
    __syncthreads();   // r_s ready

    f32x4 acc[4][4];
#pragma unroll
    for (int mi = 0; mi < 4; ++mi)
#pragma unroll
        for (int ni = 0; ni < 4; ++ni)
            acc[mi][ni] = (f32x4){0.f, 0.f, 0.f, 0.f};

    // A staging: thread t fills slot (row t>>2 [+128], chunk t&3); swizzled
    // global source so slot chunk c' holds global chunk c'^((row>>1)&3).
    const int csw  = ((t & 3) ^ ((t >> 3) & 3)) * 8;
    const unsigned short* gA = xb + (size_t)(bm0 + (t >> 2)) * D_IN + csw;
    const int wrow = wave * 16 * BKH;   // wave-uniform LDS base

    // A fragment reads: chunk slot = quad ^ ((ln15>>1)&3)  (0-conflict)
    const int ksw  = (quad ^ ((ln15 >> 1) & 3)) * 8;
    const int aoff = (wm0 + ln15) * BKH + ksw;

    // B fragment-major: tile (o/16, h) = 1KB; lane reads ln15*32+quad*8
    // ushorts within it. Fragment (ni,h) at + ni*(KTOT/32)*512 + h*512.
    const unsigned short* gBf =
        Wt + ((size_t)((bn0 + wn0) >> 4) * (KTOT >> 5)) * 512
           + ln15 * 32 + quad * 8;
#define BSTRIDE ((size_t)(KTOT >> 5) * 512)   // 256KB in ushorts per o-tile

    // Named register buffers (static indexing — rule #20).
    short8 afA[4], afB[4], bvA[4], bvB[4];

    // prologue: B(0)->bvA, stage A slots 0,1,2. Queue [B0x4,A0x2,A1x2,A2x2];
    // vmcnt(2) drains B0,A0,A1; leaves A2 = steady state entering step 0.
#pragma unroll
    for (int ni = 0; ni < 4; ++ni)
        bvA[ni] = *(const short8*)(gBf + (size_t)ni * BSTRIDE);
#pragma unroll
    for (int s = 0; s < 3; ++s) {
        load_lds16(gA + s * BKH,              &A4[s][wrow]);
        load_lds16(gA + 128 * D_IN + s * BKH, &A4[s][128 * BKH + wrow]);
    }
    asm volatile("s_waitcnt vmcnt(2)" ::: "memory");
    __builtin_amdgcn_s_barrier();
    __builtin_amdgcn_sched_barrier(0);
#pragma unroll
    for (int mi = 0; mi < 4; ++mi)
        afA[mi] = *(const short8*)(&A4[0][0] + aoff + mi * 16 * BKH);

#define MFMA4(CUR, mi_)                                                       \
    _Pragma("unroll") for (int ni = 0; ni < 4; ++ni)                          \
        acc[mi_][ni] = __builtin_amdgcn_mfma_f32_16x16x32_bf16(               \
            af##CUR[mi_], bv##CUR[ni], acc[mi_][ni], 0, 0, 0);

// Step h: [B(h+1)->bvNXT] [stage A(h+3)] lgkm0 [rescale?]
//         {MFMA quartet ; ds_read A-frag(h+1)->afNXT} x4
// Safety (1 barrier/step): wave's slot-h ds_reads done before its lgkm0(h)
// < barrier ENDW(h) < stage into that slot at h+2 (two barriers later).
#define STEP(h_, CUR, NXT, DO_STAGE, DO_BLOAD, DO_READ)                       \
  {                                                                           \
    const int hs_ = (h_) + 3;                                                 \
    const unsigned short* An_ = &A4[((h_) + 1) & 3][0];                       \
    if (DO_BLOAD) {                                                           \
      _Pragma("unroll") for (int ni = 0; ni < 4; ++ni)                        \
        bv##NXT[ni] = *(const short8*)(                                       \
            gBf + (size_t)ni * BSTRIDE + ((h_) + 1) * 512);                   \
    }                                                                         \
    if (DO_STAGE) {                                                           \
      load_lds16(gA + ((hs_) & 31) * BKH,              &A4[(hs_) & 3][wrow]); \
      load_lds16(gA + 128 * D_IN + ((hs_) & 31) * BKH,                        \
                 &A4[(hs_) & 3][128 * BKH + wrow]);                           \
    }                                                                         \
    asm volatile("s_waitcnt lgkmcnt(0)" ::: "memory");                        \
    __builtin_amdgcn_sched_barrier(0);                                        \
    if ((h_) && !((h_) & 31)) {  /* telescoping rescale at expert entry */    \
      const int e_ = (h_) >> 5;                                               \
      _Pragma("unroll") for (int mi = 0; mi < 4; ++mi) {                      \
        const f32x4 rv = *(const f32x4*)&r_s[e_][wm0 + mi * 16 + quad * 4];   \
        _Pragma("unroll") for (int ni = 0; ni < 4; ++ni)                      \
          _Pragma("unroll") for (int r = 0; r < 4; ++r)                       \
            acc[mi][ni][r] *= rv[r];                                          \
      }                                                                       \
    }                                                                         \
    __builtin_amdgcn_s_setprio(1);                                            \
    MFMA4(CUR, 0)                                                             \
    __builtin_amdgcn_sched_barrier(0);                                        \
    if (DO_READ)                                                              \
      af##NXT[0] = *(const short8*)(An_ + aoff + 0 * 16 * BKH);               \
    __builtin_amdgcn_sched_barrier(0);                                        \
    MFMA4(CUR, 1)                                                             \
    __builtin_amdgcn_sched_barrier(0);                                        \
    if (DO_READ)                                                              \
      af##NXT[1] = *(const short8*)(An_ + aoff + 1 * 16 * BKH);               \
    __builtin_amdgcn_sched_barrier(0);                                        \
    MFMA4(CUR, 2)                                                             \
    __builtin_amdgcn_sched_barrier(0);                                        \
    if (DO_READ) {                                                            \
      af##NXT[2] = *(const short8*)(An_ + aoff + 2 * 16 * BKH);               \
      af##NXT[3] = *(const short8*)(An_ + aoff + 3 * 16 * BKH);               \
    }                                                                         \
    __builtin_amdgcn_sched_barrier(0);                                        \
    MFMA4(CUR, 3)                                                             \
    __builtin_amdgcn_s_setprio(0);                                            \
    __builtin_amdgcn_sched_barrier(0);                                        \
  }

#define ENDW(N_)                                                              \
  asm volatile("s_waitcnt vmcnt(" #N_ ")" ::: "memory");                      \
  __builtin_amdgcn_s_barrier();                                               \
  __builtin_amdgcn_sched_barrier(0);

    for (int h = 0; h < NSTEP - 4; h += 2) {   // pairs (0,1)..(250,251)
        STEP(h, A, B, 1, 1, 1);
        ENDW(2);
        STEP(h + 1, B, A, 1, 1, 1);
        ENDW(2);
    }
    STEP(252, A, B, 1, 1, 1);   // stages A255 (last), loads B253
    ENDW(2);
    STEP(253, B, A, 0, 1, 1);   // loads B254, reads af254
    ENDW(0);                    // drain A255 (cluster 254 reads it) + B254
    STEP(254, A, B, 0, 1, 1);   // loads B255, reads af255
    ENDW(0);                    // drain B255
    STEP(255, B, A, 0, 0, 0);

#undef STEP
#undef MFMA4
#undef ENDW
#undef BSTRIDE

    // final telescope scale by d[7], then add sum_e g_e * b[e][col]
#pragma unroll
    for (int mi = 0; mi < 4; ++mi) {
        const f32x4 fin = *(const f32x4*)&r_s[0][wm0 + mi * 16 + quad * 4];
#pragma unroll
        for (int ni = 0; ni < 4; ++ni)
#pragma unroll
            for (int r = 0; r < 4; ++r) acc[mi][ni][r] *= fin[r];
    }
#pragma unroll
    for (int e = 0; e < N_EXP; ++e) {
        f32x4 gv[4];
        float bb[4];
#pragma unroll
        for (int mi = 0; mi < 4; ++mi)
            gv[mi] = *(const f32x4*)&g_s[e][wm0 + mi * 16 + quad * 4];
#pragma unroll
        for (int ni = 0; ni < 4; ++ni) bb[ni] = b_s[e][wn0 + ni * 16 + ln15];
#pragma unroll
        for (int mi = 0; mi < 4; ++mi)
#pragma unroll
            for (int ni = 0; ni < 4; ++ni)
#pragma unroll
                for (int r = 0; r < 4; ++r)
                    acc[mi][ni][r] += gv[mi][r] * bb[ni];
    }

#pragma unroll
    for (int mi = 0; mi < 4; ++mi) {
#pragma unroll
        for (int ni = 0; ni < 4; ++ni) {
            const int col  = bn0 + wn0 + ni * 16 + ln15;
            const int row0 = bm0 + wm0 + mi * 16 + quad * 4;
#pragma unroll
            for (int r = 0; r < 4; ++r)
                out[(size_t)(row0 + r) * D_OUT + col] = acc[mi][ni][r];
        }
    }
}

// ---------------------------------------------------------------------------
extern "C" void kernel_launch(void* const* d_in, const int* in_sizes, int n_in,
                              void* d_out, int out_size, void* d_ws, size_t ws_size,
                              hipStream_t stream) {
    const float* x  = (const float*)d_in[0];
    const float* W  = (const float*)d_in[1];
    const float* b  = (const float*)d_in[2];
    const float* gW = (const float*)d_in[3];
    const float* gb = (const float*)d_in[4];
    float* out = (float*)d_out;

    unsigned short* xb  = (unsigned short*)d_ws;                 // 16 MB
    unsigned short* Wt  = xb + (size_t)N_TOK * D_IN;             // 16 MB
    float*          g_t = (float*)(Wt + (size_t)D_OUT * KTOT);   // 256 KB

    prep_kernel<<<4096, 256, 0, stream>>>(x, gW, gb, W, xb, Wt, g_t);
    moe_gemm16_kernel<<<dim3(D_OUT / BN, N_TOK / BM), 512, 0, stream>>>(
        xb, Wt, b, g_t, out);
}

// Round 8
// 246.790 us; speedup vs baseline: 1.9013x; 1.5477x over previous
//
#include <hip/hip_runtime.h>
#include <hip/hip_bf16.h>
#include <cstdint>
#include <cstddef>

#define N_TOK 8192
#define D_IN  1024
#define D_OUT 1024
#define N_EXP 8
#define KTOT  (N_EXP * D_IN)

#define BM    256
#define BN    128
#define BKH   32          // half-K step
#define NSTEP 256         // KTOT / BKH

typedef __attribute__((ext_vector_type(8))) short short8;
typedef __attribute__((ext_vector_type(8))) unsigned short ushort8;
typedef __attribute__((ext_vector_type(4))) float f32x4;

__device__ __forceinline__ unsigned short f2bf(float f) {
    union { float f; unsigned int u; } v; v.f = f;
    return (unsigned short)((v.u + 0x7FFFu + ((v.u >> 16) & 1u)) >> 16);
}

__device__ __forceinline__ void load_lds16(const void* g, void* l) {
    __builtin_amdgcn_global_load_lds(
        (const __attribute__((address_space(1))) void*)g,
        (__attribute__((address_space(3))) void*)l,
        16, 0, 0);
}

// ---------------------------------------------------------------------------
// Fused prep, 4096 blocks. CHANGED this round (gate half only):
//   [0,2048)    : W[e][i][o] fp32 -> Wt[o][e*1024+i] bf16 (64x64 transpose)
//                 — UNCHANGED (coalesced both sides).
//   [2048,4096) : gate softmax + x->bf16, one wave per token. gW is now
//                 staged ONCE per block into LDS transposed (fp32) — the
//                 old inner loop issued 32 GLOBAL loads/lane each touching
//                 64 distinct cache lines (128B lane stride); that scatter
//                 is the theorized source of prep's ~90us excess. Now:
//                 coalesced 32KB stage + conflict-free float4 LDS reads.
// ---------------------------------------------------------------------------
__global__ __launch_bounds__(256) void prep_kernel(
    const float* __restrict__ x, const float* __restrict__ gW,
    const float* __restrict__ gbias, const float* __restrict__ W,
    unsigned short* __restrict__ xb, unsigned short* __restrict__ Wt,
    float* __restrict__ g_t) {
    const int b = blockIdx.x;
    const int t = threadIdx.x;

    __shared__ __align__(16) float smem[8 * 1028];   // 32.9 KB (union)

    if (b < 2048) {
        float (*tile)[65] = (float(*)[65])smem;
        const int e  = b >> 8;
        const int i0 = ((b >> 4) & 15) * 64;
        const int o0 = (b & 15) * 64;

        const int rr = t >> 4;
        const int rc = (t & 15) * 4;
#pragma unroll
        for (int j = 0; j < 4; ++j) {
            const float4 v = *(const float4*)(
                W + ((size_t)e * D_IN + (i0 + rr + 16 * j)) * D_OUT + o0 + rc);
            tile[rr + 16 * j][rc + 0] = v.x;
            tile[rr + 16 * j][rc + 1] = v.y;
            tile[rr + 16 * j][rc + 2] = v.z;
            tile[rr + 16 * j][rc + 3] = v.w;
        }
        __syncthreads();
        const int ow = t >> 2;
        const int c  = (t & 3) * 16;
        ushort8 v0, v1;
#pragma unroll
        for (int j = 0; j < 8; ++j) v0[j] = f2bf(tile[c + j][ow]);
#pragma unroll
        for (int j = 0; j < 8; ++j) v1[j] = f2bf(tile[c + 8 + j][ow]);
        unsigned short* dst = Wt + (size_t)(o0 + ow) * KTOT + e * D_IN + i0 + c;
        *(ushort8*)dst = v0;
        *(ushort8*)(dst + 8) = v1;
    } else {
        float (*gwT)[1028] = (float(*)[1028])smem;
        // Stage gW (32KB) coalesced: thread t reads gW[t+256r], writes
        // transposed [e][i]. One-time; replaces 8192 scattered loads/block.
#pragma unroll
        for (int r = 0; r < 32; ++r) {
            const int flat = t + 256 * r;          // = i*8 + e
            gwT[flat & 7][flat >> 3] = gW[flat];
        }
        __syncthreads();

        const int lane = t & 63;
        const int n    = (b - 2048) * 4 + (t >> 6);

        float acc[8];
#pragma unroll
        for (int e = 0; e < 8; ++e) acc[e] = 0.f;
#pragma unroll
        for (int jj = 0; jj < 4; ++jj) {
            const int i = 256 * jj + 4 * lane;
            const float4 xv = *(const float4*)(x + (size_t)n * D_IN + i);
            ushort4 u;
            u.x = f2bf(xv.x); u.y = f2bf(xv.y);
            u.z = f2bf(xv.z); u.w = f2bf(xv.w);
            *(ushort4*)(xb + (size_t)n * D_IN + i) = u;
#pragma unroll
            for (int e = 0; e < 8; ++e) {
                const float4 wv = *(const float4*)&gwT[e][i];
                acc[e] += xv.x * wv.x + xv.y * wv.y
                        + xv.z * wv.z + xv.w * wv.w;
            }
        }
#pragma unroll
        for (int off = 32; off > 0; off >>= 1) {
#pragma unroll
            for (int e = 0; e < 8; ++e) acc[e] += __shfl_down(acc[e], off);
        }
        if (lane == 0) {
            float lg[8], mx = -1e30f;
#pragma unroll
            for (int e = 0; e < 8; ++e) {
                lg[e] = acc[e] + gbias[e];
                mx = fmaxf(mx, lg[e]);
            }
            float s = 0.f;
#pragma unroll
            for (int e = 0; e < 8; ++e) { lg[e] = expf(lg[e] - mx); s += lg[e]; }
            const float inv = 1.f / s;
#pragma unroll
            for (int e = 0; e < 8; ++e)
                g_t[(size_t)e * N_TOK + n] = lg[e] * inv;
        }
    }
}

// ---------------------------------------------------------------------------
// GEMM v13 — byte-identical to the Round-5 kernel (measured 146.4us,
// MfmaUtil 41.5, 0 conflicts). BM256xBN128, 8 waves, 4 LDS slots, XCD 4Mx8N
// super-tile, A+B in LDS with XOR swizzle, interleaved MFMA/ds_read register
// double-buffer, counted vmcnt(3), telescoping rescale.
// ---------------------------------------------------------------------------
__global__ __launch_bounds__(512, 1) void moe_gemm13_kernel(
    const unsigned short* __restrict__ xb,   // [N_TOK][D_IN] bf16
    const unsigned short* __restrict__ Wt,   // [D_OUT][KTOT] bf16
    const float* __restrict__ bias,          // [N_EXP][D_OUT]
    const float* __restrict__ g_t,           // [N_EXP][N_TOK]
    float* __restrict__ out) {               // [N_TOK][D_OUT]
    __shared__ __align__(16) unsigned short A4[4][BM * BKH];  // 64 KB
    __shared__ __align__(16) unsigned short B4[4][BN * BKH];  // 32 KB
    __shared__ __align__(16) float g_s[N_EXP][BM];            // 8 KB
    __shared__ __align__(16) float r_s[N_EXP][BM];            // 8 KB
    __shared__ __align__(16) float b_s[N_EXP][BN];            // 4 KB

    const int t    = threadIdx.x;
    const int lane = t & 63;
    const int ln15 = lane & 15;
    const int quad = lane >> 4;
    const int wave = t >> 6;             // 0..7
    const int wm0  = (wave >> 1) * 64;   // 0,64,128,192
    const int wn0  = (wave & 1) * 64;    // 0,64

    // XCD super-tile: flat%8 = XCD; XCD owns M-rows [4*xcd,4*xcd+4) x 8 N-cols
    // -> per-XCD per-expert working set 4MB = L2 (R2: FETCH 533->79MB).
    const int flat = blockIdx.x + 8 * blockIdx.y;   // grid (8, 32)
    const int bn0  = ((flat >> 3) & 7) * BN;
    const int bm0  = ((flat & 7) * 4 + (flat >> 6)) * BM;

    for (int j = t; j < N_EXP * BM; j += 512)
        g_s[j >> 8][j & 255] = g_t[(size_t)(j >> 8) * N_TOK + bm0 + (j & 255)];
    for (int j = t; j < N_EXP * BN; j += 512)
        b_s[j >> 7][j & 127] = bias[(size_t)(j >> 7) * D_OUT + bn0 + (j & 127)];
    __syncthreads();
    if (t < BM) {
        float d[N_EXP];
#pragma unroll
        for (int e = 0; e < N_EXP; ++e) d[e] = fmaxf(g_s[e][t], 1e-30f);
#pragma unroll
        for (int e = 1; e < N_EXP; ++e) r_s[e][t] = d[e - 1] / d[e];
        r_s[0][t] = d[N_EXP - 1];
    }
    __syncthreads();   // r_s ready

    f32x4 acc[4][4];
#pragma unroll
    for (int mi = 0; mi < 4; ++mi)
#pragma unroll
        for (int ni = 0; ni < 4; ++ni)
            acc[mi][ni] = (f32x4){0.f, 0.f, 0.f, 0.f};

    // Staging: thread t fills slot (row t>>2, chunk t&3); swizzled global
    // source so slot chunk c' holds global chunk c'^((row>>1)&3).
    const int srow = t >> 2;
    const int csw  = ((t & 3) ^ ((t >> 3) & 3)) * 8;
    const unsigned short* gA = xb + (size_t)(bm0 + srow) * D_IN + csw;
    const unsigned short* gB = Wt + (size_t)(bn0 + srow) * (size_t)KTOT + csw;
    const int wrow = wave * 16 * BKH;   // wave-uniform LDS base

    // Fragment reads: chunk slot = quad ^ ((ln15>>1)&3)  (verified 0-conflict)
    const int ksw  = (quad ^ ((ln15 >> 1) & 3)) * 8;
    const int aoff = (wm0 + ln15) * BKH + ksw;
    const int boff = (wn0 + ln15) * BKH + ksw;

    // Two named fragment register buffers (static indexing — rule #20).
    short8 afA[4], bvA[4], afB[4], bvB[4];

    // prologue: stage slots 0,1,2; vmcnt(3) -> slots 0,1 landed; barrier;
    // read slot-0 fragments into buffer A.
#pragma unroll
    for (int s = 0; s < 3; ++s) {
        load_lds16(gA + s * BKH,              &A4[s][wrow]);
        load_lds16(gA + 128 * D_IN + s * BKH, &A4[s][128 * BKH + wrow]);
        load_lds16(gB + (size_t)s * BKH,      &B4[s][wrow]);
    }
    asm volatile("s_waitcnt vmcnt(3)" ::: "memory");
    __builtin_amdgcn_s_barrier();
    __builtin_amdgcn_sched_barrier(0);
#pragma unroll
    for (int mi = 0; mi < 4; ++mi)
        afA[mi] = *(const short8*)(&A4[0][0] + aoff + mi * 16 * BKH);
#pragma unroll
    for (int ni = 0; ni < 4; ++ni)
        bvA[ni] = *(const short8*)(&B4[0][0] + boff + ni * 16 * BKH);

#define MFMA4(CUR, mi_)                                                       \
    _Pragma("unroll") for (int ni = 0; ni < 4; ++ni)                          \
        acc[mi_][ni] = __builtin_amdgcn_mfma_f32_16x16x32_bf16(               \
            af##CUR[mi_], bv##CUR[ni], acc[mi_][ni], 0, 0, 0);

#define STEP(h_, CUR, NXT, DO_STAGE, DO_READ)                                 \
  {                                                                           \
    const int hs_ = (h_) + 3;                                                 \
    const unsigned short* An_ = &A4[((h_) + 1) & 3][0];                       \
    const unsigned short* Bn_ = &B4[((h_) + 1) & 3][0];                       \
    asm volatile("s_waitcnt lgkmcnt(0)" ::: "memory");                        \
    __builtin_amdgcn_sched_barrier(0);                                        \
    if ((h_) && !((h_) & 31)) {  /* telescoping rescale at expert entry */    \
      const int e_ = (h_) >> 5;                                               \
      _Pragma("unroll") for (int mi = 0; mi < 4; ++mi) {                      \
        const f32x4 rv = *(const f32x4*)&r_s[e_][wm0 + mi * 16 + quad * 4];   \
        _Pragma("unroll") for (int ni = 0; ni < 4; ++ni)                      \
          _Pragma("unroll") for (int r = 0; r < 4; ++r)                       \
            acc[mi][ni][r] *= rv[r];                                          \
      }                                                                       \
    }                                                                         \
    __builtin_amdgcn_s_setprio(1);                                            \
    MFMA4(CUR, 0)                                                             \
    __builtin_amdgcn_sched_barrier(0);                                        \
    if (DO_READ) {                                                            \
      af##NXT[0] = *(const short8*)(An_ + aoff + 0 * 16 * BKH);               \
      af##NXT[1] = *(const short8*)(An_ + aoff + 1 * 16 * BKH);               \
    }                                                                         \
    __builtin_amdgcn_sched_barrier(0);                                        \
    MFMA4(CUR, 1)                                                             \
    __builtin_amdgcn_sched_barrier(0);                                        \
    if (DO_READ) {                                                            \
      af##NXT[2] = *(const short8*)(An_ + aoff + 2 * 16 * BKH);               \
      af##NXT[3] = *(const short8*)(An_ + aoff + 3 * 16 * BKH);               \
    }                                                                         \
    __builtin_amdgcn_sched_barrier(0);                                        \
    MFMA4(CUR, 2)                                                             \
    __builtin_amdgcn_sched_barrier(0);                                        \
    if (DO_READ) {                                                            \
      _Pragma("unroll") for (int ni = 0; ni < 4; ++ni)                        \
        bv##NXT[ni] = *(const short8*)(Bn_ + boff + ni * 16 * BKH);           \
    }                                                                         \
    __builtin_amdgcn_sched_barrier(0);                                        \
    MFMA4(CUR, 3)                                                             \
    __builtin_amdgcn_s_setprio(0);                                            \
    __builtin_amdgcn_sched_barrier(0);                                        \
    if (DO_STAGE) {                                                           \
      load_lds16(gA + ((hs_) & 31) * BKH,              &A4[(hs_) & 3][wrow]); \
      load_lds16(gA + 128 * D_IN + ((hs_) & 31) * BKH,                        \
                 &A4[(hs_) & 3][128 * BKH + wrow]);                           \
      load_lds16(gB + (size_t)(hs_) * BKH,             &B4[(hs_) & 3][wrow]); \
    }                                                                         \
  }

#define ENDW(N_)                                                              \
  asm volatile("s_waitcnt vmcnt(" #N_ ")" ::: "memory");                      \
  __builtin_amdgcn_s_barrier();                                               \
  __builtin_amdgcn_sched_barrier(0);

    for (int h = 0; h < NSTEP - 4; h += 2) {   // pairs (0,1)..(250,251)
        STEP(h, A, B, 1, 1);
        ENDW(3);
        STEP(h + 1, B, A, 1, 1);
        ENDW(3);
    }
    STEP(252, A, B, 1, 1);   // stages slot 255 (last)
    ENDW(3);                 // stage(254) landed (read next step)
    STEP(253, B, A, 0, 1);
    ENDW(0);                 // stage(255) landed (read next step)
    STEP(254, A, B, 0, 1);   // reads slot 255; nothing outstanding -> no bar
    STEP(255, B, A, 0, 0);

#undef STEP
#undef MFMA4
#undef ENDW

    // final telescope scale by d[7], then add sum_e g_e * b[e][col]
#pragma unroll
    for (int mi = 0; mi < 4; ++mi) {
        const f32x4 fin = *(const f32x4*)&r_s[0][wm0 + mi * 16 + quad * 4];
#pragma unroll
        for (int ni = 0; ni < 4; ++ni)
#pragma unroll
            for (int r = 0; r < 4; ++r) acc[mi][ni][r] *= fin[r];
    }
#pragma unroll
    for (int e = 0; e < N_EXP; ++e) {
        f32x4 gv[4];
        float bb[4];
#pragma unroll
        for (int mi = 0; mi < 4; ++mi)
            gv[mi] = *(const f32x4*)&g_s[e][wm0 + mi * 16 + quad * 4];
#pragma unroll
        for (int ni = 0; ni < 4; ++ni) bb[ni] = b_s[e][wn0 + ni * 16 + ln15];
#pragma unroll
        for (int mi = 0; mi < 4; ++mi)
#pragma unroll
            for (int ni = 0; ni < 4; ++ni)
#pragma unroll
                for (int r = 0; r < 4; ++r)
                    acc[mi][ni][r] += gv[mi][r] * bb[ni];
    }

#pragma unroll
    for (int mi = 0; mi < 4; ++mi) {
#pragma unroll
        for (int ni = 0; ni < 4; ++ni) {
            const int col  = bn0 + wn0 + ni * 16 + ln15;
            const int row0 = bm0 + wm0 + mi * 16 + quad * 4;
#pragma unroll
            for (int r = 0; r < 4; ++r)
                out[(size_t)(row0 + r) * D_OUT + col] = acc[mi][ni][r];
        }
    }
}

// ---------------------------------------------------------------------------
extern "C" void kernel_launch(void* const* d_in, const int* in_sizes, int n_in,
                              void* d_out, int out_size, void* d_ws, size_t ws_size,
                              hipStream_t stream) {
    const float* x  = (const float*)d_in[0];
    const float* W  = (const float*)d_in[1];
    const float* b  = (const float*)d_in[2];
    const float* gW = (const float*)d_in[3];
    const float* gb = (const float*)d_in[4];
    float* out = (float*)d_out;

    unsigned short* xb  = (unsigned short*)d_ws;                 // 16 MB
    unsigned short* Wt  = xb + (size_t)N_TOK * D_IN;             // 16 MB
    float*          g_t = (float*)(Wt + (size_t)D_OUT * KTOT);   // 256 KB

    prep_kernel<<<4096, 256, 0, stream>>>(x, gW, gb, W, xb, Wt, g_t);
    moe_gemm13_kernel<<<dim3(D_OUT / BN, N_TOK / BM), 512, 0, stream>>>(
        xb, Wt, b, g_t, out);
}